// Round 3
// baseline (273.585 us; speedup 1.0000x reference)
//
#include <hip/hip_runtime.h>
#include <math.h>

// MLPEMABlock — only the ema_var path survives (both MLP branches are *0 in the ref).
//
// Stage 1: per (b,f,4096-t) block: stage x tile in LDS (padded), each lane runs the
//          exact 201-tap sliding EMA recurrence for 16 consecutive t; den via closed
//          form; outputs re-coalesced through LDS.  var -> d_ws (B,F,S).
// Stage 2: per-row v[64] in VGPRs; rms over 192 chans (128 are zero); weights read
//          as wave-uniform loads straight from lin_W (scalar path, no LDS);
//          64->128 linear + lin_b; write output & skip.

#define SB    8192
#define BB    8
#define FF    64
#define EPSF  1e-8f

#define NTB   4096              // t-range per stage1 block
#define HALO  201
#define TILE  (NTB + HALO)      // 4297
#define PADI(o) ((o) + ((o) >> 4))
#define LDSX  (PADI(TILE - 1) + 1)
#define LDSO  (PADI(NTB - 1) + 1)

__global__ __launch_bounds__(256) void ema_var_kernel(
    const float* __restrict__ x,            // (B, F, S)
    const float* __restrict__ log_hl_var,   // (F)
    float* __restrict__ var_out)            // (B, F, S) in d_ws
{
  __shared__ float xt[LDSX];
  __shared__ float ot[LDSO];

  const int tid  = threadIdx.x;
  const int bc   = blockIdx.x;            // 0 .. B*F*2 - 1  (1024)
  const int b    = bc >> 7;
  const int f    = (bc >> 1) & 63;
  const int half = bc & 1;
  const int t0   = half * NTB;
  const int g0   = t0 - HALO;             // tile start (global t), may be -201

  const float hl     = expf(log_hl_var[f]);
  const float invhl  = 1.0f / hl;
  const float alpha  = exp2f(-invhl);         // 0.5^(1/hl)
  const float a201   = exp2f(-201.0f * invhl);
  const float inv1ma = 1.0f / (1.0f - alpha);
  const float rd_st  = 1.0f / ((1.0f - a201) * inv1ma + EPSF);  // steady 1/den

  const float* __restrict__ xp = x + (long)(b * FF + f) * SB;

  // stage x[g0 .. t0+NTB) into padded LDS (zero-fill g<0); coalesced
  for (int i = tid; i < TILE; i += 256) {
    const int g = g0 + i;
    xt[PADI(i)] = (g >= 0) ? xp[g] : 0.0f;
  }
  __syncthreads();

  const int l  = tid & 63;
  const int w  = tid >> 6;
  const int t_start = t0 + w * 1024 + l * 16;
  int s0 = t_start - HALO; if (s0 < 0) s0 = 0;

  // warm-up: accumulate the full 201-tap window state n[t_start-1]
  float nx = 0.f, nx2 = 0.f;
#pragma unroll 4
  for (int s = s0; s < t_start; ++s) {
    const int o = s - g0;
    const float xv = xt[PADI(o)];
    nx  = fmaf(alpha, nx,  xv);
    nx2 = fmaf(alpha, nx2, xv * xv);
  }

  float r[16];
#pragma unroll
  for (int j = 0; j < 16; ++j) {
    const int t = t_start + j;
    const int o = t - g0;
    const float xv = xt[PADI(o)];
    const float xo = xt[PADI(o - HALO)];   // zero-filled region when t < 201
    nx  = fmaf(alpha, nx,  fmaf(-a201, xo,      xv));
    nx2 = fmaf(alpha, nx2, fmaf(-a201, xo * xo, xv * xv));
    float rd = rd_st;
    if (t < 200) {   // short window (first chunk only): den = (1-a^(t+1))/(1-a)
      const float ac = exp2f(-(float)(t + 1) * invhl);
      rd = 1.0f / ((1.0f - ac) * inv1ma + EPSF);
    }
    const float m1 = nx * rd;
    r[j] = fmaf(nx2, rd, -(m1 * m1));
  }

  // re-coalesce through LDS
  const int base = w * 1024 + l * 16;
#pragma unroll
  for (int j = 0; j < 16; ++j) ot[PADI(base + j)] = r[j];
  __syncthreads();

  float* __restrict__ vp = var_out + (long)(b * FF + f) * SB + t0;
  for (int i = tid; i < NTB; i += 256)
    vp[i] = ot[PADI(i)];
}

__global__ __launch_bounds__(256) void stage2_kernel(
    const float* __restrict__ var,      // (B, F, S) from d_ws
    const float* __restrict__ norm_w,   // (192)
    const float* __restrict__ lin_W,    // (192, 128) row-major
    const float* __restrict__ lin_b,    // (128)
    float* __restrict__ out)            // output (B,64,S) then skip (B,64,S)
{
  const int tid   = threadIdx.x;
  const int lane  = tid & 63;
  const int wv    = tid >> 6;                      // 0..3
  const int rg    = blockIdx.x * 2 + (wv >> 1);    // row-group 0..1023
  // k-half handled by this wave; readfirstlane pins it wave-uniform so the
  // weight loads below become scalar(K$)/broadcast loads.
  const int k0    = __builtin_amdgcn_readfirstlane((wv & 1) * 64);
  const int row   = rg * 64 + lane;                // 0 .. B*S-1
  const int b     = row >> 13;                     // /8192
  const int t     = row & 8191;

  const float* __restrict__ vp = var + ((long)b * FF) * SB + t;

  float v[64];
  float ss = 0.f;
#pragma unroll
  for (int f = 0; f < 64; ++f) {
    v[f] = vp[(long)f * SB];                       // coalesced across lanes
    ss = fmaf(v[f], v[f], ss);
  }
  const float inv = 1.0f / sqrtf(fmaf(ss, (1.0f / 192.0f), EPSF));

  // fold norm_w into v (uniform loads)
#pragma unroll
  for (int f = 0; f < 64; ++f) v[f] *= norm_w[128 + f];

  const long skip_base = (long)BB * 64 * SB;       // out = [output | skip]

  for (int kb = 0; kb < 64; kb += 8) {
    float acc[8] = {0.f, 0.f, 0.f, 0.f, 0.f, 0.f, 0.f, 0.f};
#pragma unroll
    for (int f = 0; f < 64; ++f) {
      // wave-uniform address -> scalar/broadcast load, overlaps with VALU
      const float* wr = lin_W + (128 + f) * 128 + k0 + kb;
      const float4 w0 = *(const float4*)wr;
      const float4 w1 = *(const float4*)(wr + 4);
      acc[0] = fmaf(v[f], w0.x, acc[0]);
      acc[1] = fmaf(v[f], w0.y, acc[1]);
      acc[2] = fmaf(v[f], w0.z, acc[2]);
      acc[3] = fmaf(v[f], w0.w, acc[3]);
      acc[4] = fmaf(v[f], w1.x, acc[4]);
      acc[5] = fmaf(v[f], w1.y, acc[5]);
      acc[6] = fmaf(v[f], w1.z, acc[6]);
      acc[7] = fmaf(v[f], w1.w, acc[7]);
    }
#pragma unroll
    for (int j = 0; j < 8; ++j) {
      const int k = k0 + kb + j;
      const float res = fmaf(acc[j], inv, lin_b[k]);
      const long dst = (k < 64)
          ? (skip_base + ((long)(b * 64 + k)) * SB + t)     // skip_y
          : (((long)(b * 64 + (k - 64))) * SB + t);         // output
      out[dst] = res;                                       // coalesced
    }
  }
}

extern "C" void kernel_launch(void* const* d_in, const int* in_sizes, int n_in,
                              void* d_out, int out_size, void* d_ws, size_t ws_size,
                              hipStream_t stream) {
  // 0:x 1:log_hl_in 2:log_hl_out 3:log_hl_var 4:W1 5:b1 6:W2 7:b2 8:norm_w 9:lin_W 10:lin_b
  const float* x          = (const float*)d_in[0];
  const float* log_hl_var = (const float*)d_in[3];
  const float* norm_w     = (const float*)d_in[8];
  const float* lin_W      = (const float*)d_in[9];
  const float* lin_b      = (const float*)d_in[10];
  float* var_ws = (float*)d_ws;               // B*F*S*4 = 16 MiB scratch
  float* out    = (float*)d_out;

  ema_var_kernel<<<dim3(BB * FF * 2), dim3(256), 0, stream>>>(x, log_hl_var, var_ws);
  stage2_kernel<<<dim3((BB * SB) / 128), dim3(256), 0, stream>>>(
      var_ws, norm_w, lin_W, lin_b, out);
}

// Round 5
// 126.799 us; speedup vs baseline: 2.1576x; 2.1576x over previous
//
#include <hip/hip_runtime.h>
#include <math.h>

// MLPEMABlock — only the ema_var path survives (both MLP branches are *0 in the ref).
//
// Stage 1: per (b,f,4096-t) block: x tile in LDS (16-pad), fixed 201-trip warm-up
//          (zero-filled halo, compile-time bounds), exact sliding 201-tap window;
//          outputs re-coalesced via float4-friendly padded LDS. var -> d_ws (B,F,S).
// Stage 2: LDS-tiled GEMM: vt[64][256] + weights(norm_w-folded) wl[64][128] in LDS,
//          thread tile 4t x 16k, acc[4][16] in VGPRs only; rms pass in LDS;
//          float4 coalesced stores of output & skip.

#define SB    8192
#define BB    8
#define FF    64
#define EPSF  1e-8f

// ---------------- stage 1 ----------------
#define NTB   4096
#define HALO  201
#define TILE  (NTB + HALO)                 // 4297
#define PADI(o) ((o) + ((o) >> 4))         // pad 1 per 16 (scalar access)
#define PADO(o) ((o) + (((o) >> 4) << 2))  // pad 4 per 16 (float4-aligned groups)
#define LDSX  (PADI(TILE - 1) + 1)
#define LDSO  (PADO(NTB - 1) + 1)

__global__ __launch_bounds__(256) void ema_var_kernel(
    const float* __restrict__ x,            // (B, F, S)
    const float* __restrict__ log_hl_var,   // (F)
    float* __restrict__ var_out)            // (B, F, S) in d_ws
{
  __shared__ float xt[LDSX];
  __shared__ float ot[LDSO];

  const int tid  = threadIdx.x;
  const int bc   = blockIdx.x;            // 0 .. B*F*2 - 1  (1024)
  const int b    = bc >> 7;
  const int f    = (bc >> 1) & 63;
  const int half = bc & 1;
  const int t0   = half * NTB;
  const int g0   = t0 - HALO;             // tile start (global t), may be -201

  const float hl     = expf(log_hl_var[f]);
  const float invhl  = 1.0f / hl;
  const float alpha  = exp2f(-invhl);         // 0.5^(1/hl)
  const float a201   = exp2f(-201.0f * invhl);
  const float inv1ma = 1.0f / (1.0f - alpha);
  const float rd_st  = 1.0f / ((1.0f - a201) * inv1ma + EPSF);  // steady 1/den

  const float* __restrict__ xp = x + (long)(b * FF + f) * SB;

  // stage x[g0 .. t0+NTB) into padded LDS (zero-fill g<0); coalesced
  for (int i = tid; i < TILE; i += 256) {
    const int g = g0 + i;
    xt[PADI(i)] = (g >= 0) ? xp[g] : 0.0f;
  }
  __syncthreads();

  const int l     = tid & 63;
  const int w     = tid >> 6;
  const int base0 = w * 1024 + l * 16;    // lane's window start, tile-local
  const int t_start = t0 + base0;

  // warm-up: FIXED 201-trip loop (zero-filled halo makes the clamp unneeded)
  float nx = 0.f, nx2 = 0.f;
#pragma unroll 4
  for (int j = 0; j < HALO; ++j) {
    const float xv = xt[PADI(base0 + j)];
    nx  = fmaf(alpha, nx,  xv);
    nx2 = fmaf(alpha, nx2, xv * xv);
  }

  float r[16];
#pragma unroll
  for (int j = 0; j < 16; ++j) {
    const int o  = base0 + HALO + j;
    const float xv = xt[PADI(o)];
    const float xo = xt[PADI(o - HALO)];   // zero-filled region when t < 201
    nx  = fmaf(alpha, nx,  fmaf(-a201, xo,      xv));
    nx2 = fmaf(alpha, nx2, fmaf(-a201, xo * xo, xv * xv));
    float rd = rd_st;
    const int t = t_start + j;
    if (t < 200) {   // short window (first 200 samples only): den=(1-a^(t+1))/(1-a)
      const float ac = exp2f(-(float)(t + 1) * invhl);
      rd = 1.0f / ((1.0f - ac) * inv1ma + EPSF);
    }
    const float m1 = nx * rd;
    r[j] = fmaf(nx2, rd, -(m1 * m1));
  }

  // re-coalesce through LDS (PADO keeps every 4-group 16B aligned)
  const int pb = PADO(base0);
#pragma unroll
  for (int j4 = 0; j4 < 4; ++j4) {
    float4 v4 = make_float4(r[j4 * 4 + 0], r[j4 * 4 + 1], r[j4 * 4 + 2], r[j4 * 4 + 3]);
    *(float4*)&ot[pb + j4 * 4] = v4;
  }
  __syncthreads();

  float* __restrict__ vp = var_out + (long)(b * FF + f) * SB + t0;
#pragma unroll
  for (int i = tid * 4; i < NTB; i += 1024) {
    float4 v4 = *(const float4*)&ot[PADO(i)];
    *(float4*)&vp[i] = v4;
  }
}

// ---------------- stage 2 ----------------
#define RT 256    // rows (t) per block

__global__ __launch_bounds__(512, 2) void stage2_kernel(
    const float* __restrict__ var,      // (B, F, S) from d_ws
    const float* __restrict__ norm_w,   // (192)
    const float* __restrict__ lin_W,    // (192, 128) row-major
    const float* __restrict__ lin_b,    // (128)
    float* __restrict__ out)            // output (B,64,S) then skip (B,64,S)
{
  __shared__ float vt[FF * RT];         // 64 KB  vt[f*256 + t]
  __shared__ float wl[FF * 128];        // 32 KB  wl[f*128 + k] = W[128+f][k]*nw[128+f]
  __shared__ float invl[RT];            // 1 KB
  __shared__ float bl[128];

  const int tid = threadIdx.x;
  const int b   = blockIdx.x >> 5;           // 32 blocks per batch (8192/256)
  const int t0  = (blockIdx.x & 31) * RT;

  const int lane = tid & 63;
  const int w    = tid >> 6;                 // wave 0..7 = k-slice

  // --- load vt: one f-row (256 floats = 64 lanes x float4) per wave per iter
  {
    const float* __restrict__ vbase = var + (long)(b * FF) * SB + t0;
#pragma unroll
    for (int f = w; f < FF; f += 8) {
      float4 v4 = *(const float4*)&vbase[(long)f * SB + lane * 4];
      *(float4*)&vt[f * RT + lane * 4] = v4;
    }
  }
  // --- load weights (fold norm_w) + bias
  {
    const float* __restrict__ wsrc = lin_W + 128 * 128;   // rows 128..191
#pragma unroll
    for (int i = tid * 4; i < FF * 128; i += 512 * 4) {
      float4 w4 = *(const float4*)&wsrc[i];
      const float nw = norm_w[128 + (i >> 7)];
      w4.x *= nw; w4.y *= nw; w4.z *= nw; w4.w *= nw;
      *(float4*)&wl[i] = w4;
    }
    if (tid < 128) bl[tid] = lin_b[tid];
  }
  __syncthreads();

  // --- rms pass: thread t (tid<256) sums 64 f; 128 of 192 ref channels are zero
  if (tid < RT) {
    float ss = 0.f;
#pragma unroll
    for (int f = 0; f < FF; ++f) {
      const float v = vt[f * RT + tid];
      ss = fmaf(v, v, ss);
    }
    invl[tid] = 1.0f / sqrtf(fmaf(ss, (1.0f / 192.0f), EPSF));
  }
  __syncthreads();

  // --- GEMM: thread tile 4t x 16k; k = w*16 + kk; t = tt*4 + j
  const int tt = lane;                        // 0..63 -> 4 t each (covers 256)
  const int k0 = w * 16;

  float acc[4][16];
#pragma unroll
  for (int j = 0; j < 4; ++j)
#pragma unroll
    for (int kk = 0; kk < 16; ++kk) acc[j][kk] = 0.f;

  for (int f = 0; f < FF; ++f) {
    const float4 va = *(const float4*)&vt[f * RT + tt * 4];     // lane-consecutive b128
    const float4 w0 = *(const float4*)&wl[f * 128 + k0 + 0];    // wave-broadcast b128
    const float4 w1 = *(const float4*)&wl[f * 128 + k0 + 4];
    const float4 w2 = *(const float4*)&wl[f * 128 + k0 + 8];
    const float4 w3 = *(const float4*)&wl[f * 128 + k0 + 12];
    const float wv[16] = { w0.x, w0.y, w0.z, w0.w, w1.x, w1.y, w1.z, w1.w,
                           w2.x, w2.y, w2.z, w2.w, w3.x, w3.y, w3.z, w3.w };
    const float vv[4] = { va.x, va.y, va.z, va.w };
#pragma unroll
    for (int j = 0; j < 4; ++j)
#pragma unroll
      for (int kk = 0; kk < 16; ++kk)
        acc[j][kk] = fmaf(vv[j], wv[kk], acc[j][kk]);
  }

  // --- epilogue: res = acc*inv[t] + b[k]; float4 coalesced stores
  const float4 inv4 = *(const float4*)&invl[tt * 4];
  const float iv[4] = { inv4.x, inv4.y, inv4.z, inv4.w };
  const long skip_base = (long)BB * 64 * SB;    // out = [output | skip]

#pragma unroll
  for (int kk = 0; kk < 16; ++kk) {
    const int k = k0 + kk;
    const float bk = bl[k];
    float4 r;
    r.x = fmaf(acc[0][kk], iv[0], bk);
    r.y = fmaf(acc[1][kk], iv[1], bk);
    r.z = fmaf(acc[2][kk], iv[2], bk);
    r.w = fmaf(acc[3][kk], iv[3], bk);
    const long dst = (k < 64)
        ? (skip_base + ((long)(b * 64 + k)) * SB + t0 + tt * 4)       // skip_y
        : (((long)(b * 64 + (k - 64))) * SB + t0 + tt * 4);           // output
    *(float4*)&out[dst] = r;
  }
}

extern "C" void kernel_launch(void* const* d_in, const int* in_sizes, int n_in,
                              void* d_out, int out_size, void* d_ws, size_t ws_size,
                              hipStream_t stream) {
  // 0:x 1:log_hl_in 2:log_hl_out 3:log_hl_var 4:W1 5:b1 6:W2 7:b2 8:norm_w 9:lin_W 10:lin_b
  const float* x          = (const float*)d_in[0];
  const float* log_hl_var = (const float*)d_in[3];
  const float* norm_w     = (const float*)d_in[8];
  const float* lin_W      = (const float*)d_in[9];
  const float* lin_b      = (const float*)d_in[10];
  float* var_ws = (float*)d_ws;               // B*F*S*4 = 16 MiB scratch
  float* out    = (float*)d_out;

  ema_var_kernel<<<dim3(BB * FF * 2), dim3(256), 0, stream>>>(x, log_hl_var, var_ws);
  stage2_kernel<<<dim3(BB * (SB / RT)), dim3(512), 0, stream>>>(
      var_ws, norm_w, lin_W, lin_b, out);
}

// Round 7
// 118.750 us; speedup vs baseline: 2.3039x; 1.0678x over previous
//
#include <hip/hip_runtime.h>
#include <math.h>

// MLPEMABlock — only the ema_var path survives (both MLP branches are *0 in the ref).
//
// Stage 1: truncated EMA via prefix subtraction:
//   p[t] = a*p[t-1] + x[t]  (untruncated scan),  n[t] = p[t] - a^201 * p[t-201].
//   Block = one (b,f) row (8192 t). 256 threads x 32-elem local scan, shfl wave
//   scan (factor a^32), cross-wave combine (a^2048). x: global->regs only.
//   LDS holds scanned prefixes, pad 1-per-32 -> stride-33 conflict-free.
// Stage 2 (unchanged, known-good): LDS-tiled GEMM vt[64][256] + wl[64][128],
//   thread tile 4t x 16k, rms pass, float4 coalesced stores.

#define SB    8192
#define BB    8
#define FF    64
#define EPSF  1e-8f
#define HALO  201

// ---------------- stage 1 ----------------
#define PAD1(o) ((o) + ((o) >> 5))
#define QLEN (PAD1(SB - 1) + 1)      // 8447 floats

__global__ __launch_bounds__(256) void ema_var_kernel(
    const float* __restrict__ x,            // (B, F, S)
    const float* __restrict__ log_hl_var,   // (F)
    float* __restrict__ var_out)            // (B, F, S) in d_ws
{
  __shared__ float qx [QLEN];
  __shared__ float qx2[QLEN];
  __shared__ float wcx[4], wcx2[4];

  const int tid  = threadIdx.x;
  const int lane = tid & 63;
  const int w    = tid >> 6;
  const int bf   = blockIdx.x;        // 0..511
  const int b    = bf >> 6;
  const int f    = bf & 63;

  const float hl     = expf(log_hl_var[f]);
  const float invhl  = 1.0f / hl;
  const float alpha  = exp2f(-invhl);            // 0.5^(1/hl)
  const float a201   = exp2f(-201.0f * invhl);
  const float inv1ma = 1.0f / (1.0f - alpha);
  const float rd_st  = 1.0f / ((1.0f - a201) * inv1ma + EPSF);
  const float m32    = exp2f(-32.0f * invhl);    // alpha^32
  const float m2048  = exp2f(-2048.0f * invhl);  // alpha^2048 (per-wave span)

  const float* __restrict__ xp = x + (long)(b * FF + f) * SB;
  const int t0 = tid * 32;

  // ---- load own 32 x values (global -> regs, dense across the wave)
  float qa[32];                        // will become qloc_x then q_x
  float q2[32];                        // qloc_x2 then q_x2
#pragma unroll
  for (int g = 0; g < 8; ++g) {
    const float4 v4 = *(const float4*)&xp[t0 + g * 4];
    qa[g*4+0] = v4.x; qa[g*4+1] = v4.y; qa[g*4+2] = v4.z; qa[g*4+3] = v4.w;
  }

  // ---- local scans: s = a*s + x ; s2 = a*s2 + x*x
  {
    float sx = 0.f, sx2 = 0.f;
#pragma unroll
    for (int j = 0; j < 32; ++j) {
      const float xv = qa[j];
      sx  = fmaf(alpha, sx,  xv);
      sx2 = fmaf(alpha, sx2, xv * xv);
      qa[j] = sx;
      q2[j] = sx2;
    }
  }

  // ---- wave scan of chunk carries with uniform factor m32
  float bx = qa[31], bx2 = q2[31];
  {
    float p = m32;
#pragma unroll
    for (int off = 1; off < 64; off <<= 1) {
      const float ux  = __shfl_up(bx,  off, 64);
      const float ux2 = __shfl_up(bx2, off, 64);
      if (lane >= off) { bx = fmaf(p, ux, bx); bx2 = fmaf(p, ux2, bx2); }
      p *= p;
    }
  }
  if (lane == 63) { wcx[w] = bx; wcx2[w] = bx2; }
  __syncthreads();

  // ---- block carry-in for this wave (serial over <=3 wave carries)
  float ax = 0.f, ax2 = 0.f;
  for (int i = 0; i < w; ++i) {
    ax  = fmaf(m2048, ax,  wcx[i]);
    ax2 = fmaf(m2048, ax2, wcx2[i]);
  }

  // ---- C_{tid-1}: prefix state just before this thread's chunk
  const float bux  = __shfl_up(bx,  1, 64);
  const float bux2 = __shfl_up(bx2, 1, 64);
  const float powl = exp2f(-32.0f * (float)lane * invhl);   // m32^lane
  float Cx, Cx2;
  if (lane == 0) { Cx = ax;                  Cx2 = ax2; }
  else           { Cx = fmaf(powl, ax, bux); Cx2 = fmaf(powl, ax2, bux2); }

  // ---- apply carry, keep q in regs, publish to LDS (stride-33: conflict-free)
  {
    float pf = alpha;
    const int base = 33 * tid;          // == PAD1(32*tid) .. contiguous 32
#pragma unroll
    for (int j = 0; j < 32; ++j) {
      const float qv  = fmaf(pf, Cx,  qa[j]);
      const float qv2 = fmaf(pf, Cx2, q2[j]);
      qa[j] = qv;  q2[j] = qv2;
      qx [base + j] = qv;
      qx2[base + j] = qv2;
      pf *= alpha;
    }
  }
  __syncthreads();

  // ---- n[t] = q[t] - a201*q[t-201]; var = E[x2] - E[x]^2
  float vr[32];
#pragma unroll
  for (int j = 0; j < 32; ++j) {
    const int t = t0 + j;
    float nqx = qa[j], nqx2 = q2[j];
    if (t >= HALO) {
      const int po = PAD1(t - HALO);    // stride-33 across lanes: conflict-free
      nqx  = fmaf(-a201, qx [po], nqx);
      nqx2 = fmaf(-a201, qx2[po], nqx2);
    }
    float rd = rd_st;
    if (t < 200) {                      // short window: den=(1-a^(t+1))/(1-a)
      rd = 1.0f / ((1.0f - exp2f(-(float)(t + 1) * invhl)) * inv1ma + EPSF);
    }
    const float m1 = nqx * rd;
    vr[j] = fmaf(nqx2, rd, -(m1 * m1));
  }
  __syncthreads();                      // all shifted reads done before overwrite

  // ---- stage var into qx (own chunk), then coalesced float4 stores
  {
    const int base = 33 * tid;
#pragma unroll
    for (int j = 0; j < 32; ++j) qx[base + j] = vr[j];
  }
  __syncthreads();

  float* __restrict__ vp = var_out + (long)(b * FF + f) * SB;
#pragma unroll
  for (int g = 0; g < 8; ++g) {
    const int i = (g * 256 + tid) * 4;  // consecutive across threads
    float4 v4;
    v4.x = qx[PAD1(i + 0)];
    v4.y = qx[PAD1(i + 1)];
    v4.z = qx[PAD1(i + 2)];
    v4.w = qx[PAD1(i + 3)];
    *(float4*)&vp[i] = v4;
  }
}

// ---------------- stage 2 (unchanged) ----------------
#define RT 256    // rows (t) per block

__global__ __launch_bounds__(512, 2) void stage2_kernel(
    const float* __restrict__ var,      // (B, F, S) from d_ws
    const float* __restrict__ norm_w,   // (192)
    const float* __restrict__ lin_W,    // (192, 128) row-major
    const float* __restrict__ lin_b,    // (128)
    float* __restrict__ out)            // output (B,64,S) then skip (B,64,S)
{
  __shared__ float vt[FF * RT];         // 64 KB  vt[f*256 + t]
  __shared__ float wl[FF * 128];        // 32 KB  wl[f*128 + k] = W[128+f][k]*nw[128+f]
  __shared__ float invl[RT];
  __shared__ float bl[128];

  const int tid = threadIdx.x;
  const int b   = blockIdx.x >> 5;           // 32 blocks per batch (8192/256)
  const int t0  = (blockIdx.x & 31) * RT;

  const int lane = tid & 63;
  const int w    = tid >> 6;                 // wave 0..7 = k-slice

  {
    const float* __restrict__ vbase = var + (long)(b * FF) * SB + t0;
#pragma unroll
    for (int f = w; f < FF; f += 8) {
      float4 v4 = *(const float4*)&vbase[(long)f * SB + lane * 4];
      *(float4*)&vt[f * RT + lane * 4] = v4;
    }
  }
  {
    const float* __restrict__ wsrc = lin_W + 128 * 128;   // rows 128..191
#pragma unroll
    for (int i = tid * 4; i < FF * 128; i += 512 * 4) {
      float4 w4 = *(const float4*)&wsrc[i];
      const float nw = norm_w[128 + (i >> 7)];
      w4.x *= nw; w4.y *= nw; w4.z *= nw; w4.w *= nw;
      *(float4*)&wl[i] = w4;
    }
    if (tid < 128) bl[tid] = lin_b[tid];
  }
  __syncthreads();

  if (tid < RT) {
    float ss = 0.f;
#pragma unroll
    for (int f = 0; f < FF; ++f) {
      const float v = vt[f * RT + tid];
      ss = fmaf(v, v, ss);
    }
    invl[tid] = 1.0f / sqrtf(fmaf(ss, (1.0f / 192.0f), EPSF));
  }
  __syncthreads();

  const int tt = lane;
  const int k0 = w * 16;

  float acc[4][16];
#pragma unroll
  for (int j = 0; j < 4; ++j)
#pragma unroll
    for (int kk = 0; kk < 16; ++kk) acc[j][kk] = 0.f;

  for (int f = 0; f < FF; ++f) {
    const float4 va = *(const float4*)&vt[f * RT + tt * 4];     // lane-consecutive b128
    const float4 w0 = *(const float4*)&wl[f * 128 + k0 + 0];    // wave-broadcast b128
    const float4 w1 = *(const float4*)&wl[f * 128 + k0 + 4];
    const float4 w2 = *(const float4*)&wl[f * 128 + k0 + 8];
    const float4 w3 = *(const float4*)&wl[f * 128 + k0 + 12];
    const float wv[16] = { w0.x, w0.y, w0.z, w0.w, w1.x, w1.y, w1.z, w1.w,
                           w2.x, w2.y, w2.z, w2.w, w3.x, w3.y, w3.z, w3.w };
    const float vv[4] = { va.x, va.y, va.z, va.w };
#pragma unroll
    for (int j = 0; j < 4; ++j)
#pragma unroll
      for (int kk = 0; kk < 16; ++kk)
        acc[j][kk] = fmaf(vv[j], wv[kk], acc[j][kk]);
  }

  const float4 inv4 = *(const float4*)&invl[tt * 4];
  const float iv[4] = { inv4.x, inv4.y, inv4.z, inv4.w };
  const long skip_base = (long)BB * 64 * SB;    // out = [output | skip]

#pragma unroll
  for (int kk = 0; kk < 16; ++kk) {
    const int k = k0 + kk;
    const float bk = bl[k];
    float4 r;
    r.x = fmaf(acc[0][kk], iv[0], bk);
    r.y = fmaf(acc[1][kk], iv[1], bk);
    r.z = fmaf(acc[2][kk], iv[2], bk);
    r.w = fmaf(acc[3][kk], iv[3], bk);
    const long dst = (k < 64)
        ? (skip_base + ((long)(b * 64 + k)) * SB + t0 + tt * 4)       // skip_y
        : (((long)(b * 64 + (k - 64))) * SB + t0 + tt * 4);           // output
    *(float4*)&out[dst] = r;
  }
}

extern "C" void kernel_launch(void* const* d_in, const int* in_sizes, int n_in,
                              void* d_out, int out_size, void* d_ws, size_t ws_size,
                              hipStream_t stream) {
  // 0:x 1:log_hl_in 2:log_hl_out 3:log_hl_var 4:W1 5:b1 6:W2 7:b2 8:norm_w 9:lin_W 10:lin_b
  const float* x          = (const float*)d_in[0];
  const float* log_hl_var = (const float*)d_in[3];
  const float* norm_w     = (const float*)d_in[8];
  const float* lin_W      = (const float*)d_in[9];
  const float* lin_b      = (const float*)d_in[10];
  float* var_ws = (float*)d_ws;               // B*F*S*4 = 16 MiB scratch
  float* out    = (float*)d_out;

  ema_var_kernel<<<dim3(BB * FF), dim3(256), 0, stream>>>(x, log_hl_var, var_ws);
  stage2_kernel<<<dim3(BB * (SB / RT)), dim3(512), 0, stream>>>(
      var_ws, norm_w, lin_W, lin_b, out);
}